// Round 10
// baseline (168.198 us; speedup 1.0000x reference)
//
#include <hip/hip_runtime.h>
#include <math.h>

namespace {

constexpr int kB    = 16384;
constexpr int kS0   = 7;
constexpr int kS1   = 7;
constexpr int kD    = 30;
constexpr int kCells = kB * kS0 * kS1;   // 802816
constexpr int TPB   = 64;                // single-wave blocks: LDS 7.68KB ->
                                         // ~20 blocks/CU (4x deeper pipeline
                                         // than TPB=256's 5), barrier = free
constexpr int NBLK  = kCells / TPB;      // 12544 (exact)
constexpr float kInv7 = 1.0f / 7.0f;
constexpr float kWC = 5.0f;
constexpr float kWN = 0.5f;

__device__ __forceinline__ float frcp(float x) {
    return __builtin_amdgcn_rcpf(x);     // v_rcp_f32, ~1e-7 rel err (2% tol)
}

__device__ __forceinline__ float sigm(float x) {
    return frcp(1.0f + __expf(-x));
}

// r5 retried WITH the two post-r5 fixes:
//  - launch_bounds(64,4): VGPR cap 128 so the ~45-VGPR load batch can live
//    (r5's default alloc chose 28 -> MLP collapsed to ~2, 99 us).
//  - sched_barrier(0) pinning all 11 global loads before the first ds_write.
__global__ void __launch_bounds__(TPB, 4) yolo_loss_kernel(
    const float* __restrict__ pred,
    const int*   __restrict__ grid,
    const float* __restrict__ tbox,
    const int*   __restrict__ tcls,
    float* __restrict__ partials)   // NBLK f32 in d_ws (all overwritten)
{
    __shared__ float sp[TPB * kD];        // 7680 B staging for pred tile

    const int tid   = threadIdx.x;        // == lane (single wave)
    const int cell0 = blockIdx.x * TPB;
    const int cell  = cell0 + tid;

    // --- coalesced load batch: 480 float4 = 64*7 + 32; branchless ragged
    // tail (lanes 32..63 redundantly load/store lanes 0..31's data: benign).
    const float4* __restrict__ g4 =
        reinterpret_cast<const float4*>(pred + (size_t)cell0 * kD);
    float4* s4 = reinterpret_cast<float4*>(sp);
    const int etid = 448 + (tid & 31);

    float4 r[8];
    #pragma unroll
    for (int k = 0; k < 7; ++k) r[k] = g4[tid + 64 * k];
    r[7] = g4[etid];

    const float4 tb4 = reinterpret_cast<const float4*>(tbox)[cell];
    const int g  = grid[cell];
    const int tc = tcls[cell];

    // all 11 global loads issued before the first ds_write (MLP ~11)
    __builtin_amdgcn_sched_barrier(0);

    #pragma unroll
    for (int k = 0; k < 7; ++k) s4[tid + 64 * k] = r[k];
    s4[etid] = r[7];
    __syncthreads();                      // single wave: just a waitcnt

    const int cj = cell % kS1;            // column -> xg
    const int ci = (cell / kS1) % kS0;    // row    -> yg

    // --- per-cell 30 floats from LDS; batch all 15 ds_read2 before use ---
    float f[kD];
    {
        const float2* p2 = reinterpret_cast<const float2*>(sp + tid * kD);
        #pragma unroll
        for (int q = 0; q < kD / 2; ++q) {
            float2 t = p2[q];
            f[2 * q]     = t.x;
            f[2 * q + 1] = t.y;
        }
        __builtin_amdgcn_sched_barrier(0);
    }

    const float tox = tb4.x, toy = tb4.y, tw = tb4.z, th = tb4.w;

    const float conf0 = sigm(f[0]);
    const float conf1 = sigm(f[1]);
    float pbx[2], pby[2], pbw[2], pbh[2];
    #pragma unroll
    for (int k = 0; k < 2; ++k) {
        pbx[k] = sigm(f[2 + 4 * k + 0]);
        pby[k] = sigm(f[2 + 4 * k + 1]);
        pbw[k] = sigm(f[2 + 4 * k + 2]);
        pbh[k] = sigm(f[2 + 4 * k + 3]);
    }

    // --- softmax over 20 classes, no max-subtraction (inputs ~N(0,1):
    // exp <= ~e^6, 20-term fp32 sum nowhere near overflow) ---
    float csum = 0.0f, et = 0.0f;
    #pragma unroll
    for (int q = 0; q < 20; ++q) {
        const float e = __expf(f[10 + q]);
        csum += e;
        et = (q == tc) ? e : et;          // constant q -> cndmask
    }
    const float cls_t = et * frcp(csum);

    // --- IOU of both predicted boxes vs target box ---
    const float x = (float)cj, y = (float)ci;
    const float tcx = (x + tox) * kInv7;
    const float tcy = (y + toy) * kInv7;
    const float thw = tw * 0.5f, thh = th * 0.5f;
    const float tarea = tw * th;

    float iou[2];
    #pragma unroll
    for (int k = 0; k < 2; ++k) {
        const float pcx = (x + pbx[k]) * kInv7;
        const float pcy = (y + pby[k]) * kInv7;
        const float pw = pbw[k], ph = pbh[k];
        const float tb_ = fminf(tcx + thw, pcx + pw * 0.5f) - fmaxf(tcx - thw, pcx - pw * 0.5f);
        const float lr_ = fminf(tcy + thh, pcy + ph * 0.5f) - fmaxf(tcy - thh, pcy - ph * 0.5f);
        float inter = tb_ * lr_;
        inter = (tb_ < 0.0f || lr_ < 0.0f) ? 0.0f : inter;
        iou[k] = inter * frcp(tarea + pw * ph - inter);
    }

    const bool b1 = (iou[1] > iou[0]);     // tie -> box 0 (first-max)
    const float bx = b1 ? pbx[1] : pbx[0];
    const float by = b1 ? pby[1] : pby[0];
    const float bw = b1 ? pbw[1] : pbw[0];
    const float bh = b1 ? pbh[1] : pbh[0];
    const float conf_b = b1 ? conf1 : conf0;
    const float iou_b  = b1 ? iou[1] : iou[0];

    const float dx = bx - tox;
    const float dy = by - toy;
    const float dw = sqrtf(bw) - sqrtf(tw);
    const float dh = sqrtf(bh) - sqrtf(th);
    const float coord = dx * dx + dy * dy + dw * dw + dh * dh;
    const float d1 = conf_b - iou_b;
    const float d2 = 1.0f - cls_t;
    const float obj   = kWC * coord + d1 * d1 + d2 * d2;
    const float noobj = kWN * (conf0 * conf0 + conf1 * conf1);

    float v = (g == 1) ? obj : noobj;

    // --- wave64 shuffle reduce, plain store (no atomics, no memset dep) ---
    #pragma unroll
    for (int off = 32; off > 0; off >>= 1) v += __shfl_down(v, off, 64);
    if (tid == 0) partials[blockIdx.x] = v;
}

__global__ void __launch_bounds__(256) finish_kernel(
    const float* __restrict__ partials, float* __restrict__ out)
{
    __shared__ float wsum[4];
    const int tid = threadIdx.x;
    float v = 0.0f;
    for (int i = tid; i < NBLK; i += 256) v += partials[i];  // 49 iters
    #pragma unroll
    for (int off = 32; off > 0; off >>= 1) v += __shfl_down(v, off, 64);
    if ((tid & 63) == 0) wsum[tid >> 6] = v;
    __syncthreads();
    if (tid == 0) out[0] = (wsum[0] + wsum[1] + wsum[2] + wsum[3]) * (1.0f / kB);
}

} // namespace

extern "C" void kernel_launch(void* const* d_in, const int* in_sizes, int n_in,
                              void* d_out, int out_size, void* d_ws, size_t ws_size,
                              hipStream_t stream) {
    const float* pred = (const float*)d_in[0];
    const int*   grid = (const int*)d_in[1];
    const float* tbox = (const float*)d_in[2];
    const int*   tcls = (const int*)d_in[3];
    float* out      = (float*)d_out;
    float* partials = (float*)d_ws;       // NBLK f32; fully overwritten

    yolo_loss_kernel<<<NBLK, TPB, 0, stream>>>(pred, grid, tbox, tcls, partials);
    finish_kernel<<<1, 256, 0, stream>>>(partials, out);
}

// Round 11
// 159.849 us; speedup vs baseline: 1.0522x; 1.0522x over previous
//
#include <hip/hip_runtime.h>
#include <math.h>

namespace {

constexpr int kB    = 16384;
constexpr int kS0   = 7;
constexpr int kS1   = 7;
constexpr int kD    = 30;
constexpr int kCells = kB * kS0 * kS1;   // 802816
constexpr int TPB   = 256;
constexpr int NBLK  = kCells / TPB;      // 3136 (exact)
constexpr float kInv7 = 1.0f / 7.0f;
constexpr float kWC = 5.0f;
constexpr float kWN = 0.5f;

__device__ __forceinline__ float frcp(float x) {
    return __builtin_amdgcn_rcpf(x);     // v_rcp_f32, ~1e-7 rel err (2% tol)
}

__device__ __forceinline__ float sigm(float x) {
    return frcp(1.0f + __expf(-x));
}

// r6's zero-LDS direct-load structure + the two post-r6 fixes that rescued
// r5's structure (r10: 99->~62 us):
//  - launch_bounds(256,4): VGPR cap 128 (r6's default alloc chose 28 ->
//    loads sunk into uses, MLP~2, TA crack cost serialized).
//  - sched_barrier(0) after the 18-load batch: all loads in flight, compute
//    drains them with fine-grained vmcnt(N) in consumption order.
// No LDS staging, NO barriers anywhere: pure dataflow. Per-thread 30 floats
// via 15 x float2 (cell*120B is always 8B-aligned).
__global__ void __launch_bounds__(TPB, 4) yolo_loss_kernel(
    const float* __restrict__ pred,
    const int*   __restrict__ grid,
    const float* __restrict__ tbox,
    const int*   __restrict__ tcls,
    float* __restrict__ partials)   // NBLK f32 in d_ws (all overwritten)
{
    __shared__ float wsum[TPB / 64];      // reduction only (16 B)

    const int tid  = threadIdx.x;
    const int cell = blockIdx.x * TPB + tid;
    const int wave = tid >> 6;
    const int lane = tid & 63;

    // --- 15 independent float2 loads straight into f[] + the 3 small loads;
    // everything issued before any use.
    const float2* __restrict__ p2 =
        reinterpret_cast<const float2*>(pred + (size_t)cell * kD);

    float f[kD];
    #pragma unroll
    for (int q = 0; q < kD / 2; ++q) {
        const float2 t = p2[q];
        f[2 * q]     = t.x;
        f[2 * q + 1] = t.y;
    }

    const float4 tb4 = reinterpret_cast<const float4*>(tbox)[cell];
    const int g  = grid[cell];
    const int tc = tcls[cell];

    __builtin_amdgcn_sched_barrier(0);    // 18 loads in flight; none sunk

    const int cj = cell % kS1;            // column -> xg
    const int ci = (cell / kS1) % kS0;    // row    -> yg
    const float tox = tb4.x, toy = tb4.y, tw = tb4.z, th = tb4.w;

    const float conf0 = sigm(f[0]);
    const float conf1 = sigm(f[1]);
    float pbx[2], pby[2], pbw[2], pbh[2];
    #pragma unroll
    for (int k = 0; k < 2; ++k) {
        pbx[k] = sigm(f[2 + 4 * k + 0]);
        pby[k] = sigm(f[2 + 4 * k + 1]);
        pbw[k] = sigm(f[2 + 4 * k + 2]);
        pbh[k] = sigm(f[2 + 4 * k + 3]);
    }

    // --- softmax over 20 classes, no max-subtraction (inputs ~N(0,1):
    // exp <= ~e^6, 20-term fp32 sum nowhere near overflow) ---
    float csum = 0.0f, et = 0.0f;
    #pragma unroll
    for (int q = 0; q < 20; ++q) {
        const float e = __expf(f[10 + q]);
        csum += e;
        et = (q == tc) ? e : et;          // constant q -> cndmask
    }
    const float cls_t = et * frcp(csum);

    // --- IOU of both predicted boxes vs target box ---
    const float x = (float)cj, y = (float)ci;
    const float tcx = (x + tox) * kInv7;
    const float tcy = (y + toy) * kInv7;
    const float thw = tw * 0.5f, thh = th * 0.5f;
    const float tarea = tw * th;

    float iou[2];
    #pragma unroll
    for (int k = 0; k < 2; ++k) {
        const float pcx = (x + pbx[k]) * kInv7;
        const float pcy = (y + pby[k]) * kInv7;
        const float pw = pbw[k], ph = pbh[k];
        const float tb_ = fminf(tcx + thw, pcx + pw * 0.5f) - fmaxf(tcx - thw, pcx - pw * 0.5f);
        const float lr_ = fminf(tcy + thh, pcy + ph * 0.5f) - fmaxf(tcy - thh, pcy - ph * 0.5f);
        float inter = tb_ * lr_;
        inter = (tb_ < 0.0f || lr_ < 0.0f) ? 0.0f : inter;
        iou[k] = inter * frcp(tarea + pw * ph - inter);
    }

    const bool b1 = (iou[1] > iou[0]);     // tie -> box 0 (first-max)
    const float bx = b1 ? pbx[1] : pbx[0];
    const float by = b1 ? pby[1] : pby[0];
    const float bw = b1 ? pbw[1] : pbw[0];
    const float bh = b1 ? pbh[1] : pbh[0];
    const float conf_b = b1 ? conf1 : conf0;
    const float iou_b  = b1 ? iou[1] : iou[0];

    const float dx = bx - tox;
    const float dy = by - toy;
    const float dw = sqrtf(bw) - sqrtf(tw);
    const float dh = sqrtf(bh) - sqrtf(th);
    const float coord = dx * dx + dy * dy + dw * dw + dh * dh;
    const float d1 = conf_b - iou_b;
    const float d2 = 1.0f - cls_t;
    const float obj   = kWC * coord + d1 * d1 + d2 * d2;
    const float noobj = kWN * (conf0 * conf0 + conf1 * conf1);

    float v = (g == 1) ? obj : noobj;

    // --- wave64 shuffle reduce, cross-wave via tiny LDS, plain store ---
    #pragma unroll
    for (int off = 32; off > 0; off >>= 1) v += __shfl_down(v, off, 64);
    if (lane == 0) wsum[wave] = v;
    __syncthreads();
    if (tid == 0) {
        partials[blockIdx.x] = wsum[0] + wsum[1] + wsum[2] + wsum[3];
    }
}

__global__ void __launch_bounds__(256) finish_kernel(
    const float* __restrict__ partials, float* __restrict__ out)
{
    __shared__ float wsum[4];
    const int tid = threadIdx.x;
    float v = 0.0f;
    for (int i = tid; i < NBLK; i += 256) v += partials[i];  // 13 iters
    #pragma unroll
    for (int off = 32; off > 0; off >>= 1) v += __shfl_down(v, off, 64);
    if ((tid & 63) == 0) wsum[tid >> 6] = v;
    __syncthreads();
    if (tid == 0) out[0] = (wsum[0] + wsum[1] + wsum[2] + wsum[3]) * (1.0f / kB);
}

} // namespace

extern "C" void kernel_launch(void* const* d_in, const int* in_sizes, int n_in,
                              void* d_out, int out_size, void* d_ws, size_t ws_size,
                              hipStream_t stream) {
    const float* pred = (const float*)d_in[0];
    const int*   grid = (const int*)d_in[1];
    const float* tbox = (const float*)d_in[2];
    const int*   tcls = (const int*)d_in[3];
    float* out      = (float*)d_out;
    float* partials = (float*)d_ws;       // NBLK f32; fully overwritten

    yolo_loss_kernel<<<NBLK, TPB, 0, stream>>>(pred, grid, tbox, tcls, partials);
    finish_kernel<<<1, 256, 0, stream>>>(partials, out);
}